// Round 1
// baseline (344.193 us; speedup 1.0000x reference)
//
#include <hip/hip_runtime.h>
#include <math.h>

// EthicalGNN: encoder -> 3x(GAT + BN (+ReLU)) -> mean-pool -> 2 MLP heads.
// R8: gather restructured to 1 wave/node, 4 nodes per 256-block. Each edge row
// is read 16B/lane by HC/8 lanes (uint4), so one wave VMEM instruction covers
// 2 rows (C=64) or 4 rows (C=32); col list preloaded once per node and
// distributed via shfl (col removed from the dependent chain); e/exp computed
// once per (edge,head) instead of per 16 lanes; no LDS combine / syncthreads.
// 10 kernels + 1 memset.

#define H4 4  // heads

static __device__ __forceinline__ unsigned short f2bf(float f) {
  unsigned u = __float_as_uint(f);
  u += 0x7fffu + ((u >> 16) & 1u);  // round-to-nearest-even
  return (unsigned short)(u >> 16);
}

static __device__ __forceinline__ float bfh(unsigned u) {  // low bf16 -> f32
  return __uint_as_float(u << 16);
}
static __device__ __forceinline__ float bfl(unsigned u) {  // high bf16 -> f32
  return __uint_as_float(u & 0xffff0000u);
}

static __device__ __forceinline__ float eweight(float a) {
  a = (a > 0.f) ? a : 0.2f * a;  // leaky_relu 0.2
  return __expf(a);
}

static __device__ __forceinline__ void acc8(float* acc, float e, uint4 u) {
  acc[0] += e * bfh(u.x); acc[1] += e * bfl(u.x);
  acc[2] += e * bfh(u.y); acc[3] += e * bfl(u.y);
  acc[4] += e * bfh(u.z); acc[5] += e * bfl(u.z);
  acc[6] += e * bfh(u.w); acc[7] += e * bfl(u.w);
}

// ---------------- CSR build ----------------
__global__ void k_count(const int* __restrict__ dst, int* __restrict__ deg, int E) {
  int gid = blockIdx.x * blockDim.x + threadIdx.x;
  if (gid < E) atomicAdd(&deg[dst[gid]], 1);
}

// Parallel region allocator (wave shfl-scan + one atomicAdd per wave).
// Blocks 0..2 additionally precompute was/wad[k,h] = sum_c W[k,h*C+c]*a[h,c]
// for layer = blockIdx.x (reassociated attention logits).
__global__ void k_alloc(int* __restrict__ cursor, int* __restrict__ rbeg,
                        int* __restrict__ rend, int* __restrict__ col,
                        int* __restrict__ counter, int N,
                        const float* __restrict__ W0, const float* __restrict__ as0, const float* __restrict__ ad0,
                        const float* __restrict__ W1, const float* __restrict__ as1, const float* __restrict__ ad1,
                        const float* __restrict__ W2, const float* __restrict__ as2, const float* __restrict__ ad2,
                        float* __restrict__ pas, float* __restrict__ pad) {
  int gid = blockIdx.x * blockDim.x + threadIdx.x;
  int lane = threadIdx.x & 63;
  int size = (gid < N) ? (cursor[gid] + 1) : 0;  // +1 = self-loop
  int v = size;
#pragma unroll
  for (int off = 1; off < 64; off <<= 1) {
    int t = __shfl_up(v, off, 64);
    if (lane >= off) v += t;
  }
  int tot = __shfl(v, 63, 64);
  int base = 0;
  if (lane == 63) base = atomicAdd(counter, tot);
  base = __shfl(base, 63, 64);
  if (gid < N) {
    int p = base + v - size;  // exclusive prefix
    rbeg[gid] = p;
    rend[gid] = p + size;
    col[p] = gid;             // self-loop slot
    cursor[gid] = p + 1;
  }
  // logit-projection prep (one layer per block, threads = (k,h) pairs)
  if (blockIdx.x < 3) {
    int l = blockIdx.x;
    const float* W  = (l == 0) ? W0 : (l == 1) ? W1 : W2;
    const float* ap = (l == 0) ? as0 : (l == 1) ? as1 : as2;
    const float* dp = (l == 0) ? ad0 : (l == 1) ? ad1 : ad2;
    int HC = (l == 2) ? 128 : 256;
    int C  = HC / H4;
    int tid = threadIdx.x;  // k*4 + h
    int k = tid >> 2, h = tid & 3;
    float vs = 0.f, vd = 0.f;
    for (int c = 0; c < C; ++c) {
      float w = W[k * HC + h * C + c];
      vs += w * ap[h * C + c];
      vd += w * dp[h * C + c];
    }
    pas[l * 256 + tid] = vs;
    pad[l * 256 + tid] = vd;
  }
}

__global__ void k_scatter(const int* __restrict__ src, const int* __restrict__ dst,
                          int* __restrict__ cursor, int* __restrict__ col, int E) {
  int gid = blockIdx.x * blockDim.x + threadIdx.x;
  if (gid < E) {
    int p = atomicAdd(&cursor[dst[gid]], 1);
    col[p] = src[gid];
  }
}

// ---------------- fused GEMM + attention logits ----------------
// xp(bf16) = hin @ W ; als/ald = hin @ was/wad (64 threads, from LDS hs).
template <int HC, bool ENC>
__global__ void k_gemm_al(const float* __restrict__ hin,
                          const float* __restrict__ encW, const float* __restrict__ encb,
                          const float* __restrict__ W,
                          const float* __restrict__ was, const float* __restrict__ wad,
                          unsigned short* __restrict__ xpb,
                          float* __restrict__ als, float* __restrict__ ald, int N) {
  constexpr int K = 64, NB = 16;
  __shared__ float hs[NB * K];
  int n0 = blockIdx.x * NB;
  int tid = threadIdx.x;  // output column
  if (ENC) {
    for (int idx = tid; idx < NB * K; idx += HC) {
      int i = idx >> 6, j = idx & 63;
      int n = n0 + i;
      float a = 0.f;
      if (n < N) {
        a = encb[j];
#pragma unroll
        for (int k = 0; k < 5; ++k) a += hin[n * 5 + k] * encW[k * 64 + j];
      }
      hs[idx] = a;
    }
  } else {
    for (int idx = tid; idx < NB * K; idx += HC) {
      int n = n0 + (idx >> 6);
      hs[idx] = (n < N) ? hin[(size_t)n0 * K + idx] : 0.f;
    }
  }
  __syncthreads();
  float acc[NB];
#pragma unroll
  for (int i = 0; i < NB; ++i) acc[i] = 0.f;
  for (int k = 0; k < K; k += 4) {
    float w0 = W[(k + 0) * HC + tid];
    float w1 = W[(k + 1) * HC + tid];
    float w2 = W[(k + 2) * HC + tid];
    float w3 = W[(k + 3) * HC + tid];
#pragma unroll
    for (int i = 0; i < NB; ++i) {
      float4 hv = *(const float4*)&hs[i * K + k];
      acc[i] += hv.x * w0 + hv.y * w1 + hv.z * w2 + hv.w * w3;
    }
  }
#pragma unroll
  for (int i = 0; i < NB; ++i) {
    int n = n0 + i;
    if (n < N) xpb[(size_t)n * HC + tid] = f2bf(acc[i]);
  }
  // logits: 64 threads cover (node i, head h) pairs; dot from LDS
  if (tid < NB * H4) {
    int i = tid >> 2, h = tid & 3;
    int n = n0 + i;
    float vs = 0.f, vd = 0.f;
#pragma unroll 8
    for (int k = 0; k < K; ++k) {
      float hv = hs[i * K + k];
      vs += hv * was[k * 4 + h];
      vd += hv * wad[k * 4 + h];
    }
    if (n < N) {
      als[n * H4 + h] = vs;
      ald[n * H4 + h] = vd;
    }
  }
}

// ---------------- gather: 1 wave per node, 4 nodes per block ----------------
// Edge row (HC bf16) read 16B/lane by LPE=HC/8 lanes; EPW=64/LPE edges per
// wave-pass (2 for C=64, 4 for C=32). col preloaded into a register per 64-edge
// chunk and distributed via shfl. alpha = exp(lrelu(als[src]+ald[n]))/(sum+eps).
template <int C, bool RELU, bool POOL>
__global__ __launch_bounds__(256) void k_gather(
    const unsigned short* __restrict__ xpb,
    const float* __restrict__ als, const float* __restrict__ ald,
    const int* __restrict__ rbeg, const int* __restrict__ rend,
    const int* __restrict__ col,
    const float* __restrict__ bias, const float* __restrict__ g,
    const float* __restrict__ be, const float* __restrict__ m,
    const float* __restrict__ v, float* __restrict__ hout,
    float* __restrict__ gpart, int N) {
  constexpr int HC = H4 * C;
  constexpr int LPE = HC / 8;    // lanes per edge-row (8 bf16 = 16B per lane)
  constexpr int EPW = 64 / LPE;  // edges per pass: 2 (C=64) or 4 (C=32)
  int wid = threadIdx.x >> 6;
  int n = blockIdx.x * 4 + wid;
  if (n >= N) return;
  int lane = threadIdx.x & 63;
  int eidx = lane / LPE;   // which edge of the pass this lane serves
  int sl = lane % LPE;     // 16B slot within the row
  int head = (sl * 8) / C;
  float aldn = ald[n * H4 + head];
  int beg = rbeg[n], end = rend[n];

  float s = 0.f;
  float acc[8];
#pragma unroll
  for (int i = 0; i < 8; ++i) acc[i] = 0.f;

  for (int cb = beg; cb < end; cb += 64) {
    int clen = end - cb;
    if (clen > 64) clen = 64;
    int cidx = (lane < clen) ? col[cb + lane] : 0;
    int t = 0;
    // full groups: 4 passes = 4*EPW edges, loads batched for ILP
    for (; t + 4 * EPW <= clen; t += 4 * EPW) {
      int i0 = t + eidx;
      int s0 = __shfl(cidx, i0, 64);
      int s1 = __shfl(cidx, i0 + EPW, 64);
      int s2 = __shfl(cidx, i0 + 2 * EPW, 64);
      int s3 = __shfl(cidx, i0 + 3 * EPW, 64);
      float a0 = als[s0 * H4 + head];
      float a1 = als[s1 * H4 + head];
      float a2 = als[s2 * H4 + head];
      float a3 = als[s3 * H4 + head];
      uint4 u0 = *(const uint4*)(xpb + (size_t)s0 * HC + sl * 8);
      uint4 u1 = *(const uint4*)(xpb + (size_t)s1 * HC + sl * 8);
      uint4 u2 = *(const uint4*)(xpb + (size_t)s2 * HC + sl * 8);
      uint4 u3 = *(const uint4*)(xpb + (size_t)s3 * HC + sl * 8);
      float e0 = eweight(a0 + aldn);
      float e1 = eweight(a1 + aldn);
      float e2 = eweight(a2 + aldn);
      float e3 = eweight(a3 + aldn);
      s += (e0 + e1) + (e2 + e3);
      acc8(acc, e0, u0);
      acc8(acc, e1, u1);
      acc8(acc, e2, u2);
      acc8(acc, e3, u3);
    }
    // guarded tail passes
    for (; t < clen; t += EPW) {
      int idx = t + eidx;
      int ii = (idx < clen) ? idx : 0;
      int s0 = __shfl(cidx, ii, 64);
      float a0 = als[s0 * H4 + head];
      uint4 u0 = *(const uint4*)(xpb + (size_t)s0 * HC + sl * 8);
      float e0 = (idx < clen) ? eweight(a0 + aldn) : 0.f;
      s += e0;
      acc8(acc, e0, u0);
    }
  }

  // combine edge groups (eidx bits: 32 for C=64; 16,32 for C=32)
  if constexpr (EPW == 4) {
    s += __shfl_xor(s, 16, 64);
#pragma unroll
    for (int i = 0; i < 8; ++i) acc[i] += __shfl_xor(acc[i], 16, 64);
  }
  s += __shfl_xor(s, 32, 64);
#pragma unroll
  for (int i = 0; i < 8; ++i) acc[i] += __shfl_xor(acc[i], 32, 64);

  // per-head softmax normalization, then mean over heads
  float inv = 1.f / (s + 1e-16f);
#pragma unroll
  for (int i = 0; i < 8; ++i) acc[i] *= inv;
  // head bits of lane: C/8 and C/4 (8,16 for C=64; 4,8 for C=32)
#pragma unroll
  for (int i = 0; i < 8; ++i) acc[i] += __shfl_xor(acc[i], C / 8, 64);
#pragma unroll
  for (int i = 0; i < 8; ++i) acc[i] += __shfl_xor(acc[i], C / 4, 64);

  if (lane < C / 8) {
    int c0 = lane * 8;
    float o[8];
#pragma unroll
    for (int i = 0; i < 8; ++i) {
      int cc = c0 + i;
      float t = acc[i] * (1.f / H4) + bias[cc];
      t = (t - m[cc]) * rsqrtf(v[cc] + 1e-5f) * g[cc] + be[cc];
      if (RELU) t = fmaxf(t, 0.f);
      o[i] = t;
      if (POOL) atomicAdd(&gpart[(n & 255) * 32 + cc], t);
    }
    *(float4*)&hout[(size_t)n * C + c0] = make_float4(o[0], o[1], o[2], o[3]);
    *(float4*)&hout[(size_t)n * C + c0 + 4] = make_float4(o[4], o[5], o[6], o[7]);
  }
}

// ---------------- graph_emb + 2 MLP heads (reads bucketed partials) ----------------
__global__ void k_heads2(const float* __restrict__ gpart,
                         const float* __restrict__ eW1, const float* __restrict__ eb1,
                         const float* __restrict__ eW2, const float* __restrict__ eb2,
                         const float* __restrict__ mW1, const float* __restrict__ mb1,
                         const float* __restrict__ mW2, const float* __restrict__ mb2,
                         float* __restrict__ out, int N) {
  __shared__ float red[256];
  __shared__ float z[32];
  __shared__ float hid[32];  // [0:16) ethics, [16:32) manip
  int tid = threadIdx.x;
  int c = tid & 31;
  float s = 0.f;
  for (int b = tid >> 5; b < 256; b += 8) s += gpart[b * 32 + c];
  red[tid] = s;
  __syncthreads();
  size_t base = (size_t)N * 32;
  if (tid < 32) {
    float t = 0.f;
#pragma unroll
    for (int i = 0; i < 8; ++i) t += red[i * 32 + tid];
    t /= (float)N;
    z[tid] = t;
    out[base + tid] = t;  // graph_emb
  }
  __syncthreads();
  if (tid < 16) {
    float a = eb1[tid], b = mb1[tid];
    for (int k = 0; k < 32; ++k) {
      a += z[k] * eW1[k * 16 + tid];
      b += z[k] * mW1[k * 16 + tid];
    }
    hid[tid] = fmaxf(a, 0.f);
    hid[16 + tid] = fmaxf(b, 0.f);
  }
  __syncthreads();
  if (tid == 0) {
    float a = eb2[0];
    for (int k = 0; k < 16; ++k) a += hid[k] * eW2[k];
    out[base + 32] = 1.f / (1.f + __expf(-a));
  } else if (tid == 1) {
    float a = mb2[0];
    for (int k = 0; k < 16; ++k) a += hid[16 + k] * mW2[k];
    out[base + 33] = 1.f / (1.f + __expf(-a));
  }
}

extern "C" void kernel_launch(void* const* d_in, const int* in_sizes, int n_in,
                              void* d_out, int out_size, void* d_ws, size_t ws_size,
                              hipStream_t stream) {
  const int N = in_sizes[0] / 5;   // x is (N,5)
  const int E = in_sizes[1] / 2;   // edge_index is (2,E)
  const int M = E + N;             // CSR slots incl. self-loops

  const float* x = (const float*)d_in[0];
  const int* ei = (const int*)d_in[1];
  const int* e_src = ei;
  const int* e_dst = ei + E;
  const float* encW = (const float*)d_in[2];
  const float* encb = (const float*)d_in[3];
  const float* Wl[3]; const float* asl[3]; const float* adl[3]; const float* bl[3];
  const float* gl[3]; const float* bel[3]; const float* ml[3]; const float* vl[3];
  for (int l = 0; l < 3; ++l) {
    const int o = 4 + 8 * l;
    Wl[l]  = (const float*)d_in[o + 0];
    asl[l] = (const float*)d_in[o + 1];
    adl[l] = (const float*)d_in[o + 2];
    bl[l]  = (const float*)d_in[o + 3];
    gl[l]  = (const float*)d_in[o + 4];
    bel[l] = (const float*)d_in[o + 5];
    ml[l]  = (const float*)d_in[o + 6];
    vl[l]  = (const float*)d_in[o + 7];
  }
  const float* eW1 = (const float*)d_in[28];
  const float* eb1 = (const float*)d_in[29];
  const float* eW2 = (const float*)d_in[30];
  const float* eb2 = (const float*)d_in[31];
  const float* mW1 = (const float*)d_in[32];
  const float* mb1 = (const float*)d_in[33];
  const float* mW2 = (const float*)d_in[34];
  const float* mb2 = (const float*)d_in[35];

  float* out = (float*)d_out;

  // workspace layout: floats, then int region, then gpart (memset w/ cursor)
  float* wf = (float*)d_ws;
  size_t off = 0;
  float* hA   = wf + off; off += (size_t)N * 64;
  float* hB   = wf + off; off += (size_t)N * 64;
  unsigned short* xpb = (unsigned short*)(wf + off); off += (size_t)N * 128;  // N*256 bf16
  float* als  = wf + off; off += (size_t)N * 4;
  float* ald  = wf + off; off += (size_t)N * 4;
  float* pas  = wf + off; off += 3 * 256;
  float* pad  = wf + off; off += 3 * 256;
  int* wi = (int*)(wf + off);
  int* col     = wi;                     // M
  int* rbeg    = col + M;                // N
  int* rend    = rbeg + N;               // N
  int* cursor  = rend + N;               // N (deg before alloc)  } zeroed by
  int* counter = cursor + N;             // 1                     } one memset
  float* gpart = (float*)(counter + 1);  // 256*32                } (contiguous)

  const int T = 256;
  const int gE  = (E + T - 1) / T;
  const int gN  = (N + T - 1) / T;
  const int gGE = (N + 15) / 16;
  const int gGA = (N + 3) / 4;  // gather: 4 nodes (waves) per block

  // ---- CSR build (memset covers cursor, counter, gpart) ----
  hipMemsetAsync(cursor, 0, (size_t)(N + 1) * sizeof(int) + 256 * 32 * sizeof(float), stream);
  k_count<<<gE, T, 0, stream>>>(e_dst, cursor, E);
  k_alloc<<<gN, T, 0, stream>>>(cursor, rbeg, rend, col, counter, N,
                                Wl[0], asl[0], adl[0], Wl[1], asl[1], adl[1],
                                Wl[2], asl[2], adl[2], pas, pad);
  k_scatter<<<gE, T, 0, stream>>>(e_src, e_dst, cursor, col, E);

  // ---- layer 0 (encoder fused; 64 -> 64, HC=256) ----
  k_gemm_al<256, true><<<gGE, 256, 0, stream>>>(x, encW, encb, Wl[0], pas, pad,
                                                xpb, als, ald, N);
  k_gather<64, true, false><<<gGA, 256, 0, stream>>>(xpb, als, ald, rbeg, rend, col,
                                                     bl[0], gl[0], bel[0], ml[0], vl[0],
                                                     hB, gpart, N);

  // ---- layer 1 (64 -> 64, HC=256) ----
  k_gemm_al<256, false><<<gGE, 256, 0, stream>>>(hB, encW, encb, Wl[1], pas + 256, pad + 256,
                                                 xpb, als, ald, N);
  k_gather<64, true, false><<<gGA, 256, 0, stream>>>(xpb, als, ald, rbeg, rend, col,
                                                     bl[1], gl[1], bel[1], ml[1], vl[1],
                                                     hA, gpart, N);

  // ---- layer 2 (64 -> 32, HC=128), writes final h into d_out + pooled buckets ----
  k_gemm_al<128, false><<<gGE, 128, 0, stream>>>(hA, encW, encb, Wl[2], pas + 512, pad + 512,
                                                 xpb, als, ald, N);
  k_gather<32, false, true><<<gGA, 256, 0, stream>>>(xpb, als, ald, rbeg, rend, col,
                                                     bl[2], gl[2], bel[2], ml[2], vl[2],
                                                     out, gpart, N);

  // ---- heads ----
  k_heads2<<<1, 256, 0, stream>>>(gpart, eW1, eb1, eW2, eb2, mW1, mb1, mW2, mb2, out, N);
}

// Round 2
// 338.861 us; speedup vs baseline: 1.0157x; 1.0157x over previous
//
#include <hip/hip_runtime.h>
#include <math.h>

// EthicalGNN: encoder -> 3x(GAT + BN (+ReLU)) -> mean-pool -> 2 MLP heads.
// R9: gather keeps R7's 2-waves/node 128-thread shape (max resident waves)
// but doubles per-wave memory-level parallelism: the wave's col sub-range is
// preloaded once (coalesced) and distributed via shfl (col removed from the
// dependent chain), and 8 edges' als+xpb loads are issued per batch instead
// of 4 behind a serializing col fetch. 10 kernels + 1 memset.

#define H4 4  // heads

static __device__ __forceinline__ unsigned short f2bf(float f) {
  unsigned u = __float_as_uint(f);
  u += 0x7fffu + ((u >> 16) & 1u);  // round-to-nearest-even
  return (unsigned short)(u >> 16);
}

static __device__ __forceinline__ float bfh(unsigned u) {  // low bf16 -> f32
  return __uint_as_float(u << 16);
}
static __device__ __forceinline__ float bfl(unsigned u) {  // high bf16 -> f32
  return __uint_as_float(u & 0xffff0000u);
}

static __device__ __forceinline__ float eweight(float a) {
  a = (a > 0.f) ? a : 0.2f * a;  // leaky_relu 0.2
  return __expf(a);
}

// ---------------- CSR build ----------------
__global__ void k_count(const int* __restrict__ dst, int* __restrict__ deg, int E) {
  int gid = blockIdx.x * blockDim.x + threadIdx.x;
  if (gid < E) atomicAdd(&deg[dst[gid]], 1);
}

// Parallel region allocator (wave shfl-scan + one atomicAdd per wave).
// Blocks 0..2 additionally precompute was/wad[k,h] = sum_c W[k,h*C+c]*a[h,c]
// for layer = blockIdx.x (reassociated attention logits).
__global__ void k_alloc(int* __restrict__ cursor, int* __restrict__ rbeg,
                        int* __restrict__ rend, int* __restrict__ col,
                        int* __restrict__ counter, int N,
                        const float* __restrict__ W0, const float* __restrict__ as0, const float* __restrict__ ad0,
                        const float* __restrict__ W1, const float* __restrict__ as1, const float* __restrict__ ad1,
                        const float* __restrict__ W2, const float* __restrict__ as2, const float* __restrict__ ad2,
                        float* __restrict__ pas, float* __restrict__ pad) {
  int gid = blockIdx.x * blockDim.x + threadIdx.x;
  int lane = threadIdx.x & 63;
  int size = (gid < N) ? (cursor[gid] + 1) : 0;  // +1 = self-loop
  int v = size;
#pragma unroll
  for (int off = 1; off < 64; off <<= 1) {
    int t = __shfl_up(v, off, 64);
    if (lane >= off) v += t;
  }
  int tot = __shfl(v, 63, 64);
  int base = 0;
  if (lane == 63) base = atomicAdd(counter, tot);
  base = __shfl(base, 63, 64);
  if (gid < N) {
    int p = base + v - size;  // exclusive prefix
    rbeg[gid] = p;
    rend[gid] = p + size;
    col[p] = gid;             // self-loop slot
    cursor[gid] = p + 1;
  }
  // logit-projection prep (one layer per block, threads = (k,h) pairs)
  if (blockIdx.x < 3) {
    int l = blockIdx.x;
    const float* W  = (l == 0) ? W0 : (l == 1) ? W1 : W2;
    const float* ap = (l == 0) ? as0 : (l == 1) ? as1 : as2;
    const float* dp = (l == 0) ? ad0 : (l == 1) ? ad1 : ad2;
    int HC = (l == 2) ? 128 : 256;
    int C  = HC / H4;
    int tid = threadIdx.x;  // k*4 + h
    int k = tid >> 2, h = tid & 3;
    float vs = 0.f, vd = 0.f;
    for (int c = 0; c < C; ++c) {
      float w = W[k * HC + h * C + c];
      vs += w * ap[h * C + c];
      vd += w * dp[h * C + c];
    }
    pas[l * 256 + tid] = vs;
    pad[l * 256 + tid] = vd;
  }
}

__global__ void k_scatter(const int* __restrict__ src, const int* __restrict__ dst,
                          int* __restrict__ cursor, int* __restrict__ col, int E) {
  int gid = blockIdx.x * blockDim.x + threadIdx.x;
  if (gid < E) {
    int p = atomicAdd(&cursor[dst[gid]], 1);
    col[p] = src[gid];
  }
}

// ---------------- fused GEMM + attention logits ----------------
// xp(bf16) = hin @ W ; als/ald = hin @ was/wad (64 threads, from LDS hs).
template <int HC, bool ENC>
__global__ void k_gemm_al(const float* __restrict__ hin,
                          const float* __restrict__ encW, const float* __restrict__ encb,
                          const float* __restrict__ W,
                          const float* __restrict__ was, const float* __restrict__ wad,
                          unsigned short* __restrict__ xpb,
                          float* __restrict__ als, float* __restrict__ ald, int N) {
  constexpr int K = 64, NB = 16;
  __shared__ float hs[NB * K];
  int n0 = blockIdx.x * NB;
  int tid = threadIdx.x;  // output column
  if (ENC) {
    for (int idx = tid; idx < NB * K; idx += HC) {
      int i = idx >> 6, j = idx & 63;
      int n = n0 + i;
      float a = 0.f;
      if (n < N) {
        a = encb[j];
#pragma unroll
        for (int k = 0; k < 5; ++k) a += hin[n * 5 + k] * encW[k * 64 + j];
      }
      hs[idx] = a;
    }
  } else {
    for (int idx = tid; idx < NB * K; idx += HC) {
      int n = n0 + (idx >> 6);
      hs[idx] = (n < N) ? hin[(size_t)n0 * K + idx] : 0.f;
    }
  }
  __syncthreads();
  float acc[NB];
#pragma unroll
  for (int i = 0; i < NB; ++i) acc[i] = 0.f;
  for (int k = 0; k < K; k += 4) {
    float w0 = W[(k + 0) * HC + tid];
    float w1 = W[(k + 1) * HC + tid];
    float w2 = W[(k + 2) * HC + tid];
    float w3 = W[(k + 3) * HC + tid];
#pragma unroll
    for (int i = 0; i < NB; ++i) {
      float4 hv = *(const float4*)&hs[i * K + k];
      acc[i] += hv.x * w0 + hv.y * w1 + hv.z * w2 + hv.w * w3;
    }
  }
#pragma unroll
  for (int i = 0; i < NB; ++i) {
    int n = n0 + i;
    if (n < N) xpb[(size_t)n * HC + tid] = f2bf(acc[i]);
  }
  // logits: 64 threads cover (node i, head h) pairs; dot from LDS
  if (tid < NB * H4) {
    int i = tid >> 2, h = tid & 3;
    int n = n0 + i;
    float vs = 0.f, vd = 0.f;
#pragma unroll 8
    for (int k = 0; k < K; ++k) {
      float hv = hs[i * K + k];
      vs += hv * was[k * 4 + h];
      vd += hv * wad[k * 4 + h];
    }
    if (n < N) {
      als[n * H4 + h] = vs;
      ald[n * H4 + h] = vd;
    }
  }
}

// ---------------- gather: 2 waves per node, split edge range ----------------
// lane = h*16 + c4. alpha = exp(lrelu(als[src]+ald[n])) / (sum + 1e-16).
// Per wave: col sub-range preloaded coalesced into a register, distributed via
// shfl; 8 edges of als+xpb loads in flight per batch (no serializing col load).
template <int C, bool RELU, bool POOL>
__global__ __launch_bounds__(128) void k_gather(
    const unsigned short* __restrict__ xpb,
    const float* __restrict__ als, const float* __restrict__ ald,
    const int* __restrict__ rbeg, const int* __restrict__ rend,
    const int* __restrict__ col,
    const float* __restrict__ bias, const float* __restrict__ g,
    const float* __restrict__ be, const float* __restrict__ m,
    const float* __restrict__ v, float* __restrict__ hout,
    float* __restrict__ gpart, int N) {
  constexpr int HC = H4 * C;
  constexpr int VPL = HC / 64;  // 4 (C=64) or 2 (C=32)
  __shared__ float accbuf[64 * VPL];
  __shared__ float sbuf[H4];
  int sub = threadIdx.x >> 6;   // 0 or 1
  int lane = threadIdx.x & 63;
  int n = blockIdx.x;
  int h = lane >> 4;
  float aldn = ald[n * H4 + h];
  int beg = rbeg[n], end = rend[n];
  int len = end - beg;
  int lenA = (len + 1) >> 1;
  int jb = sub ? (beg + lenA) : beg;
  int je = sub ? end : (beg + lenA);

  float s = 0.f;
  float acc[VPL];
#pragma unroll
  for (int i = 0; i < VPL; ++i) acc[i] = 0.f;

  for (int cb = jb; cb < je; cb += 64) {
    int clen = je - cb;
    if (clen > 64) clen = 64;
    int cvec = (lane < clen) ? col[cb + lane] : 0;  // one coalesced load
    for (int t = 0; t < clen; t += 8) {
      int sv[8];
      float av[8];
#pragma unroll
      for (int i = 0; i < 8; ++i) {
        int idx = t + i;
        sv[i] = __shfl(cvec, (idx < clen) ? idx : 0, 64);
      }
#pragma unroll
      for (int i = 0; i < 8; ++i) av[i] = als[sv[i] * H4 + h];
      if constexpr (VPL == 4) {
        uint2 uv[8];
#pragma unroll
        for (int i = 0; i < 8; ++i)
          uv[i] = *(const uint2*)(xpb + (size_t)sv[i] * HC + lane * 4);
#pragma unroll
        for (int i = 0; i < 8; ++i) {
          float e = (t + i < clen) ? eweight(av[i] + aldn) : 0.f;
          s += e;
          acc[0] += e * bfh(uv[i].x);
          acc[1] += e * bfl(uv[i].x);
          acc[2] += e * bfh(uv[i].y);
          acc[3] += e * bfl(uv[i].y);
        }
      } else {
        unsigned uw[8];
#pragma unroll
        for (int i = 0; i < 8; ++i)
          uw[i] = *(const unsigned*)(xpb + (size_t)sv[i] * HC + lane * 2);
#pragma unroll
        for (int i = 0; i < 8; ++i) {
          float e = (t + i < clen) ? eweight(av[i] + aldn) : 0.f;
          s += e;
          acc[0] += e * bfh(uw[i]);
          acc[1] += e * bfl(uw[i]);
        }
      }
    }
  }

  // combine wave1 -> wave0
  if (sub) {
    if ((lane & 15) == 0) sbuf[h] = s;
#pragma unroll
    for (int i = 0; i < VPL; ++i) accbuf[lane * VPL + i] = acc[i];
  }
  __syncthreads();
  if (sub) return;
  s += sbuf[h];
#pragma unroll
  for (int i = 0; i < VPL; ++i) acc[i] += accbuf[lane * VPL + i];

  float inv = 1.f / (s + 1e-16f);
#pragma unroll
  for (int i = 0; i < VPL; ++i) {
    acc[i] *= inv;
    acc[i] += __shfl_xor(acc[i], 16, 64);  // head sum (bits 4,5 = head)
    acc[i] += __shfl_xor(acc[i], 32, 64);
  }

  if (lane < 16) {
    int c0 = lane * VPL;
    float o[VPL];
#pragma unroll
    for (int i = 0; i < VPL; ++i) {
      int cc = c0 + i;
      float t = acc[i] * (1.f / H4) + bias[cc];
      t = (t - m[cc]) * rsqrtf(v[cc] + 1e-5f) * g[cc] + be[cc];
      if (RELU) t = fmaxf(t, 0.f);
      o[i] = t;
      if (POOL) atomicAdd(&gpart[(n & 255) * 32 + cc], t);
    }
    if constexpr (VPL == 4)
      *(float4*)&hout[(size_t)n * C + c0] = make_float4(o[0], o[1], o[2], o[3]);
    else
      *(float2*)&hout[(size_t)n * C + c0] = make_float2(o[0], o[1]);
  }
}

// ---------------- graph_emb + 2 MLP heads (reads bucketed partials) ----------------
__global__ void k_heads2(const float* __restrict__ gpart,
                         const float* __restrict__ eW1, const float* __restrict__ eb1,
                         const float* __restrict__ eW2, const float* __restrict__ eb2,
                         const float* __restrict__ mW1, const float* __restrict__ mb1,
                         const float* __restrict__ mW2, const float* __restrict__ mb2,
                         float* __restrict__ out, int N) {
  __shared__ float red[256];
  __shared__ float z[32];
  __shared__ float hid[32];  // [0:16) ethics, [16:32) manip
  int tid = threadIdx.x;
  int c = tid & 31;
  float s = 0.f;
  for (int b = tid >> 5; b < 256; b += 8) s += gpart[b * 32 + c];
  red[tid] = s;
  __syncthreads();
  size_t base = (size_t)N * 32;
  if (tid < 32) {
    float t = 0.f;
#pragma unroll
    for (int i = 0; i < 8; ++i) t += red[i * 32 + tid];
    t /= (float)N;
    z[tid] = t;
    out[base + tid] = t;  // graph_emb
  }
  __syncthreads();
  if (tid < 16) {
    float a = eb1[tid], b = mb1[tid];
    for (int k = 0; k < 32; ++k) {
      a += z[k] * eW1[k * 16 + tid];
      b += z[k] * mW1[k * 16 + tid];
    }
    hid[tid] = fmaxf(a, 0.f);
    hid[16 + tid] = fmaxf(b, 0.f);
  }
  __syncthreads();
  if (tid == 0) {
    float a = eb2[0];
    for (int k = 0; k < 16; ++k) a += hid[k] * eW2[k];
    out[base + 32] = 1.f / (1.f + __expf(-a));
  } else if (tid == 1) {
    float a = mb2[0];
    for (int k = 0; k < 16; ++k) a += hid[16 + k] * mW2[k];
    out[base + 33] = 1.f / (1.f + __expf(-a));
  }
}

extern "C" void kernel_launch(void* const* d_in, const int* in_sizes, int n_in,
                              void* d_out, int out_size, void* d_ws, size_t ws_size,
                              hipStream_t stream) {
  const int N = in_sizes[0] / 5;   // x is (N,5)
  const int E = in_sizes[1] / 2;   // edge_index is (2,E)
  const int M = E + N;             // CSR slots incl. self-loops

  const float* x = (const float*)d_in[0];
  const int* ei = (const int*)d_in[1];
  const int* e_src = ei;
  const int* e_dst = ei + E;
  const float* encW = (const float*)d_in[2];
  const float* encb = (const float*)d_in[3];
  const float* Wl[3]; const float* asl[3]; const float* adl[3]; const float* bl[3];
  const float* gl[3]; const float* bel[3]; const float* ml[3]; const float* vl[3];
  for (int l = 0; l < 3; ++l) {
    const int o = 4 + 8 * l;
    Wl[l]  = (const float*)d_in[o + 0];
    asl[l] = (const float*)d_in[o + 1];
    adl[l] = (const float*)d_in[o + 2];
    bl[l]  = (const float*)d_in[o + 3];
    gl[l]  = (const float*)d_in[o + 4];
    bel[l] = (const float*)d_in[o + 5];
    ml[l]  = (const float*)d_in[o + 6];
    vl[l]  = (const float*)d_in[o + 7];
  }
  const float* eW1 = (const float*)d_in[28];
  const float* eb1 = (const float*)d_in[29];
  const float* eW2 = (const float*)d_in[30];
  const float* eb2 = (const float*)d_in[31];
  const float* mW1 = (const float*)d_in[32];
  const float* mb1 = (const float*)d_in[33];
  const float* mW2 = (const float*)d_in[34];
  const float* mb2 = (const float*)d_in[35];

  float* out = (float*)d_out;

  // workspace layout: floats, then int region, then gpart (memset w/ cursor)
  float* wf = (float*)d_ws;
  size_t off = 0;
  float* hA   = wf + off; off += (size_t)N * 64;
  float* hB   = wf + off; off += (size_t)N * 64;
  unsigned short* xpb = (unsigned short*)(wf + off); off += (size_t)N * 128;  // N*256 bf16
  float* als  = wf + off; off += (size_t)N * 4;
  float* ald  = wf + off; off += (size_t)N * 4;
  float* pas  = wf + off; off += 3 * 256;
  float* pad  = wf + off; off += 3 * 256;
  int* wi = (int*)(wf + off);
  int* col     = wi;                     // M
  int* rbeg    = col + M;                // N
  int* rend    = rbeg + N;               // N
  int* cursor  = rend + N;               // N (deg before alloc)  } zeroed by
  int* counter = cursor + N;             // 1                     } one memset
  float* gpart = (float*)(counter + 1);  // 256*32                } (contiguous)

  const int T = 256;
  const int gE  = (E + T - 1) / T;
  const int gN  = (N + T - 1) / T;
  const int gGE = (N + 15) / 16;

  // ---- CSR build (memset covers cursor, counter, gpart) ----
  hipMemsetAsync(cursor, 0, (size_t)(N + 1) * sizeof(int) + 256 * 32 * sizeof(float), stream);
  k_count<<<gE, T, 0, stream>>>(e_dst, cursor, E);
  k_alloc<<<gN, T, 0, stream>>>(cursor, rbeg, rend, col, counter, N,
                                Wl[0], asl[0], adl[0], Wl[1], asl[1], adl[1],
                                Wl[2], asl[2], adl[2], pas, pad);
  k_scatter<<<gE, T, 0, stream>>>(e_src, e_dst, cursor, col, E);

  // ---- layer 0 (encoder fused; 64 -> 64, HC=256) ----
  k_gemm_al<256, true><<<gGE, 256, 0, stream>>>(x, encW, encb, Wl[0], pas, pad,
                                                xpb, als, ald, N);
  k_gather<64, true, false><<<N, 128, 0, stream>>>(xpb, als, ald, rbeg, rend, col,
                                                   bl[0], gl[0], bel[0], ml[0], vl[0],
                                                   hB, gpart, N);

  // ---- layer 1 (64 -> 64, HC=256) ----
  k_gemm_al<256, false><<<gGE, 256, 0, stream>>>(hB, encW, encb, Wl[1], pas + 256, pad + 256,
                                                 xpb, als, ald, N);
  k_gather<64, true, false><<<N, 128, 0, stream>>>(xpb, als, ald, rbeg, rend, col,
                                                   bl[1], gl[1], bel[1], ml[1], vl[1],
                                                   hA, gpart, N);

  // ---- layer 2 (64 -> 32, HC=128), writes final h into d_out + pooled buckets ----
  k_gemm_al<128, false><<<gGE, 128, 0, stream>>>(hA, encW, encb, Wl[2], pas + 512, pad + 512,
                                                 xpb, als, ald, N);
  k_gather<32, false, true><<<N, 128, 0, stream>>>(xpb, als, ald, rbeg, rend, col,
                                                   bl[2], gl[2], bel[2], ml[2], vl[2],
                                                   out, gpart, N);

  // ---- heads ----
  k_heads2<<<1, 256, 0, stream>>>(gpart, eW1, eb1, eW2, eb2, mW1, mb1, mW2, mb2, out, N);
}